// Round 9
// baseline (510.610 us; speedup 1.0000x reference)
//
#include <hip/hip_runtime.h>
#include <hip/hip_cooperative_groups.h>
#include <math.h>
#include <stdint.h>

namespace cg = cooperative_groups;

#define F_DIM 64
#define K_CL 16
#define B_GR 16
#define SR32 68   // LDS row stride in u32 (272 B: 16B-aligned rows, conflict-free writes)

typedef _Float16 h16;
using f16x8 = __attribute__((ext_vector_type(8))) _Float16;
using f32x4 = __attribute__((ext_vector_type(4))) float;

union H8 { f16x8 v; unsigned short s[8]; uint32_t u[4]; };

struct ShP1  { float Wl[F_DIM * K_CL]; float bl[K_CL]; };
struct ShP2a { float redx[4096]; float CCl[256]; };
struct ShP2b { uint32_t AB[4 * 16 * SR32]; float CCl[256]; };   // 18432 B
struct ShP3  { float ddl[256]; float sp[16]; float cl[16]; float orr[16]; };

// ---------------------------------------------------------------------------
// Phased kernel. phase<0: cooperative, all phases with grid.sync().
// phase 1/2/3: that phase only (fallback multi-dispatch mode).
// P0 zero -> P1 assign -> P2a node stats (fp32) + P2b edges (MFMA) -> P3.
// ---------------------------------------------------------------------------
__global__ __launch_bounds__(256, 4) void mega(
    const float* __restrict__ x, const float* __restrict__ W, const float* __restrict__ bvec,
    const float* __restrict__ ew, const int* __restrict__ erow, const int* __restrict__ ecol,
    h16* __restrict__ sshr, h16* __restrict__ sshs,
    float* __restrict__ accbase,   // outx(16384) | oadj(4096) | CCb(4096)
    float* __restrict__ out,
    int Ntot, int npg, int edges_per_graph, int edges_per_block, int nmask, int phase)
{
    cg::grid_group grid = cg::this_grid();
    __shared__ __align__(16) union { ShP1 a; ShP2a b; ShP2b c; ShP3 d; } sh;

    const bool coop = (phase < 0);
    float* outx = accbase;
    float* oadj = accbase + 16384;
    float* CCb  = accbase + 16384 + 4096;

    int t = threadIdx.x;
    int bid = blockIdx.x;
    int gt = bid * 256 + t;
    int gstride = (int)gridDim.x * 256;
    int wid = t >> 6, lane = t & 63;

    // ---------------- P0: zero accumulators (coop only) -------------------
    if (coop) {
        for (int i0 = gt; i0 < 24576; i0 += gstride) accbase[i0] = 0.f;
        grid.sync();
    }

    // ---------------- P1: assign (s = xW+b, softmax, f16 writes) ----------
    if (coop || phase == 1) {
        float* Wl = sh.a.Wl;
        float* bl = sh.a.bl;
        for (int idx = t; idx < F_DIM * K_CL; idx += 256) Wl[idx] = W[idx];
        if (t < K_CL) bl[t] = bvec[t];
        __syncthreads();

        for (int i0 = gt; i0 < Ntot; i0 += gstride) {
            size_t i = (size_t)i0;
            float s[16];
#pragma unroll
            for (int k = 0; k < 16; ++k) s[k] = bl[k];

            const float4* xp = reinterpret_cast<const float4*>(x + i * F_DIM);
#pragma unroll
            for (int j = 0; j < 16; ++j) {
                float4 q = xp[j];
                float xf[4] = {q.x, q.y, q.z, q.w};
#pragma unroll
                for (int ff = 0; ff < 4; ++ff) {
                    int f = j * 4 + ff;
                    float xv = xf[ff];
                    const float4* wr = reinterpret_cast<const float4*>(&Wl[f * K_CL]);
                    float4 w0 = wr[0], w1 = wr[1], w2 = wr[2], w3 = wr[3];
                    s[0]  += xv * w0.x; s[1]  += xv * w0.y; s[2]  += xv * w0.z; s[3]  += xv * w0.w;
                    s[4]  += xv * w1.x; s[5]  += xv * w1.y; s[6]  += xv * w1.z; s[7]  += xv * w1.w;
                    s[8]  += xv * w2.x; s[9]  += xv * w2.y; s[10] += xv * w2.z; s[11] += xv * w2.w;
                    s[12] += xv * w3.x; s[13] += xv * w3.y; s[14] += xv * w3.z; s[15] += xv * w3.w;
                }
            }

            f16x8 hr0, hr1;
#pragma unroll
            for (int k = 0; k < 8; ++k) { hr0[k] = (h16)s[k]; hr1[k] = (h16)s[k + 8]; }

            float m = s[0];
#pragma unroll
            for (int k = 1; k < 16; ++k) m = fmaxf(m, s[k]);
            float sum = 0.f;
#pragma unroll
            for (int k = 0; k < 16; ++k) { s[k] = __expf(s[k] - m); sum += s[k]; }
            float inv = 1.0f / sum;

            f16x8 hs0, hs1;
#pragma unroll
            for (int k = 0; k < 8; ++k) { hs0[k] = (h16)(s[k] * inv); hs1[k] = (h16)(s[k + 8] * inv); }

            f16x8* rp = reinterpret_cast<f16x8*>(sshr + i * K_CL);
            rp[0] = hr0; rp[1] = hr1;
            f16x8* sp = reinterpret_cast<f16x8*>(sshs + i * K_CL);
            sp[0] = hs0; sp[1] = hs1;
        }
        __syncthreads();
    }
    if (coop) grid.sync();

    // ---------------- P2a: node stats fp32: outx = sraw^T x, CC = ss^T ss -
    if (coop || phase == 2) {
        float* redx = sh.b.redx;
        float* CCl  = sh.b.CCl;
        CCl[t] = 0.f;
        __syncthreads();

        int g4 = lane >> 4, l = lane & 15;
        int npb = Ntot / (int)gridDim.x;
        int npw = npb >> 2;
        size_t basen = (size_t)bid * npb + (size_t)wid * npw;

        float accx[16];
#pragma unroll
        for (int k = 0; k < 16; ++k) accx[k] = 0.f;
        float accc[4] = {0.f, 0.f, 0.f, 0.f};

        for (int j = 0; j < npw; ++j) {
            size_t i = basen + j;
            float xv = x[i * F_DIM + lane];
            const f16x8* rp = reinterpret_cast<const f16x8*>(sshr + i * K_CL);
            f16x8 r0 = rp[0], r1 = rp[1];
#pragma unroll
            for (int k = 0; k < 8; ++k) accx[k]     += (float)r0[k] * xv;
#pragma unroll
            for (int k = 0; k < 8; ++k) accx[k + 8] += (float)r1[k] * xv;

            float sv = (float)sshs[i * K_CL + l];
            accc[0] += __shfl(sv, g4 * 4 + 0, 16) * sv;
            accc[1] += __shfl(sv, g4 * 4 + 1, 16) * sv;
            accc[2] += __shfl(sv, g4 * 4 + 2, 16) * sv;
            accc[3] += __shfl(sv, g4 * 4 + 3, 16) * sv;
        }

#pragma unroll
        for (int k = 0; k < 16; ++k) redx[wid * 1024 + k * 64 + lane] = accx[k];
#pragma unroll
        for (int j4 = 0; j4 < 4; ++j4)
            atomicAdd(&CCl[(g4 * 4 + j4) * 16 + l], accc[j4]);
        __syncthreads();

        int g = (int)(((size_t)bid * npb) / (size_t)npg);
        float* dst = outx + g * (K_CL * F_DIM);
#pragma unroll
        for (int it = 0; it < 4; ++it) {
            int idx = t + it * 256;
            float v = redx[idx] + redx[1024 + idx] + redx[2048 + idx] + redx[3072 + idx];
            atomicAdd(dst + idx, v);
        }
        atomicAdd(&CCb[g * 256 + t], CCl[t]);
        __syncthreads();   // protect LDS union before P2b

        // ------------ P2b: edges via MFMA, u32-packed A|B LDS staging -----
        {
            float* CClE = sh.c.CCl;
            uint32_t* ABw = &sh.c.AB[wid * 16 * SR32];
            CClE[t] = 0.f;
            __syncthreads();

            int xcd = bid & 7;
            int slot = bid >> 3;
            int graph = xcd + 8 * (slot & 1);
            int chunk = slot >> 1;
            int q4 = lane >> 4, mm = lane & 15;

            int epw = edges_per_block >> 2;
            size_t base = (size_t)graph * edges_per_graph
                        + (size_t)chunk * edges_per_block
                        + (size_t)wid * epw;

            const f16x8* sshp = reinterpret_cast<const f16x8*>(sshs);
            f32x4 acc = {0.f, 0.f, 0.f, 0.f};

            for (int e0 = 0; e0 < epw; e0 += 64) {
                size_t eb = base + e0 + lane;
                int   r = erow[eb] & nmask;
                int   c = ecol[eb] & nmask;
                float w = ew[eb];

                f16x8 a0 = sshp[2 * (size_t)r];
                f16x8 a1 = sshp[2 * (size_t)r + 1];
                f16x8 b0 = sshp[2 * (size_t)c];
                f16x8 b1 = sshp[2 * (size_t)c + 1];
                h16 wh = (h16)w;
                a0 = a0 * wh;
                a1 = a1 * wh;

                H8 A0, A1, B0, B1;
                A0.v = a0; A1.v = a1; B0.v = b0; B1.v = b1;
#pragma unroll
                for (int k = 0; k < 8; ++k) {
                    ABw[k * SR32 + lane]       = (uint32_t)A0.s[k] | ((uint32_t)B0.s[k] << 16);
                    ABw[(k + 8) * SR32 + lane] = (uint32_t)A1.s[k] | ((uint32_t)B1.s[k] << 16);
                }

#pragma unroll
                for (int h = 0; h < 2; ++h) {
                    const uint32_t* rowp = &ABw[mm * SR32 + h * 32 + q4 * 8];
                    uint4 p0 = *(const uint4*)rowp;
                    uint4 p1 = *(const uint4*)(rowp + 4);
                    H8 Af, Bf;
                    Af.u[0] = (p0.x & 0xffffu) | (p0.y << 16);
                    Bf.u[0] = (p0.x >> 16)    | (p0.y & 0xffff0000u);
                    Af.u[1] = (p0.z & 0xffffu) | (p0.w << 16);
                    Bf.u[1] = (p0.z >> 16)    | (p0.w & 0xffff0000u);
                    Af.u[2] = (p1.x & 0xffffu) | (p1.y << 16);
                    Bf.u[2] = (p1.x >> 16)    | (p1.y & 0xffff0000u);
                    Af.u[3] = (p1.z & 0xffffu) | (p1.w << 16);
                    Bf.u[3] = (p1.z >> 16)    | (p1.w & 0xffff0000u);
                    acc = __builtin_amdgcn_mfma_f32_16x16x32_f16(Af.v, Bf.v, acc, 0, 0, 0);
                }
            }

#pragma unroll
            for (int rg = 0; rg < 4; ++rg)
                atomicAdd(&CClE[(q4 * 4 + rg) * 16 + mm], acc[rg]);
            __syncthreads();
            atomicAdd(oadj + graph * 256 + t, CClE[t]);
            __syncthreads();
        }
    }
    if (coop) grid.sync();

    // ---------------- P3: selu + losses + out_adj_norm --------------------
    if (coop || phase == 3) {
        for (int gid = gt; gid < B_GR * K_CL * F_DIM; gid += gstride) {
            float v = outx[gid];
            float r = (v > 0.f) ? (1.0507009873554805f * v)
                                : (1.0507009873554805f * 1.6732632423543772f * (__expf(v) - 1.0f));
            out[gid] = r;
        }

        if (bid == (int)gridDim.x - 1) {
            int b = t >> 4, k = t & 15;
            const float* oar = oadj + b * 256 + k * 16;
            const float* ccr = CCb + b * 256 + k * 16;

            float rowsum_off = 0.f, trace_c = 0.f, rowsum_all = 0.f, fro2 = 0.f, colsum = 0.f;
            float csv = 0.f;
#pragma unroll
            for (int l = 0; l < 16; ++l) {
                float v = oar[l];
                rowsum_all += v;
                if (l == k) trace_c = v; else rowsum_off += v;
                float c = ccr[l];
                fro2 += c * c;
                csv += c;                      // cluster_size[k] = sum_l CC[k][l]
                colsum += oadj[b * 256 + l * 16 + k];
            }
            float dd = sqrtf(rowsum_off) + 1e-12f;
            sh.d.ddl[t] = dd;

            float ds2 = colsum * colsum, cs2 = csv * csv;
            float tr = trace_c, m2 = rowsum_all;
#pragma unroll
            for (int msk = 8; msk >= 1; msk >>= 1) {
                tr   += __shfl_xor(tr,   msk, 16);
                ds2  += __shfl_xor(ds2,  msk, 16);
                cs2  += __shfl_xor(cs2,  msk, 16);
                fro2 += __shfl_xor(fro2, msk, 16);
                m2   += __shfl_xor(m2,   msk, 16);
            }
            float invfro = 1.0f / sqrtf(fro2);
            float osum = 0.f;
#pragma unroll
            for (int l = 0; l < 16; ++l) {
                float v = ccr[l] * invfro - ((l == k) ? 0.25f : 0.f);
                osum += v * v;
            }
#pragma unroll
            for (int msk = 8; msk >= 1; msk >>= 1) osum += __shfl_xor(osum, msk, 16);

            if (k == 0) {
                sh.d.sp[b]  = tr / m2 - ds2 / (m2 * m2);
                sh.d.cl[b]  = sqrtf(cs2) / (float)npg * 4.0f - 1.0f;
                sh.d.orr[b] = sqrtf(osum);
            }
            __syncthreads();
            if (t == 0) {
                float a = 0.f, c = 0.f, o = 0.f;
                for (int i2 = 0; i2 < B_GR; ++i2) { a += sh.d.sp[i2]; c += sh.d.cl[i2]; o += sh.d.orr[i2]; }
                out[20480] = -a / 16.f;
                out[20481] = c / 16.f;
                out[20482] = o / 16.f;
            }

#pragma unroll
            for (int l = 0; l < 16; ++l) {
                float v = (l == k) ? 0.f : oar[l] / (dd * sh.d.ddl[b * 16 + l]);
                out[16384 + b * 256 + k * 16 + l] = v;
            }
        }
    }
}

// ---------------------------------------------------------------------------
extern "C" void kernel_launch(void* const* d_in, const int* in_sizes, int n_in,
                              void* d_out, int out_size, void* d_ws, size_t ws_size,
                              hipStream_t stream)
{
    const float* x    = (const float*)d_in[0];
    const float* W    = (const float*)d_in[1];
    const float* bvec = (const float*)d_in[2];
    const float* ew   = (const float*)d_in[3];
    const int* erow   = (const int*)d_in[4];
    const int* ecol   = (const int*)d_in[5];

    int Ntot = in_sizes[0] / F_DIM;           // 131072
    size_t E = (size_t)in_sizes[3];           // 4194304
    int npg  = Ntot / B_GR;                   // 8192
    int epg  = (int)(E / B_GR);               // 262144
    int nmask = Ntot - 1;

    char* ws = (char*)d_ws;
    size_t o = 0;
    h16*   sshr = (h16*)(ws + o);   o += (size_t)Ntot * 16 * 2;
    h16*   sshs = (h16*)(ws + o);   o += (size_t)Ntot * 16 * 2;
    float* acc  = (float*)(ws + o); o += (size_t)24576 * 4;
    float* outp = (float*)d_out;

    // size the cooperative grid from the runtime's occupancy query
    int bpc = 0;
    hipError_t qe = hipOccupancyMaxActiveBlocksPerMultiprocessor(
        &bpc, (const void*)mega, 256, 0);
    int GRID = 1024;
    if (qe == hipSuccess && bpc > 0) {
        int maxg = bpc * 256;
        while (GRID > maxg && GRID > 128) GRID >>= 1;
        if (GRID > maxg) GRID = 0;
    } else {
        GRID = 0;
    }

    hipError_t le = hipErrorUnknown;
    int epb_c = (GRID > 0) ? (int)(E / GRID) : 0;
    int phase_c = -1;
    if (GRID >= 128) {
        void* args[] = {
            (void*)&x, (void*)&W, (void*)&bvec, (void*)&ew, (void*)&erow, (void*)&ecol,
            (void*)&sshr, (void*)&sshs, (void*)&acc, (void*)&outp,
            (void*)&Ntot, (void*)&npg, (void*)&epg, (void*)&epb_c,
            (void*)&nmask, (void*)&phase_c
        };
        le = hipLaunchCooperativeKernel((const void*)mega, dim3(GRID), dim3(256),
                                        args, 0, stream);
    }

    if (le != hipSuccess) {
        // fallback: phase dispatches (proven multi-kernel path)
        hipMemsetAsync(acc, 0, 24576 * sizeof(float), stream);
        mega<<<512, 256, 0, stream>>>(x, W, bvec, ew, erow, ecol, sshr, sshs, acc, outp,
                                      Ntot, npg, epg, 0, nmask, 1);
        mega<<<1024, 256, 0, stream>>>(x, W, bvec, ew, erow, ecol, sshr, sshs, acc, outp,
                                       Ntot, npg, epg, (int)(E / 1024), nmask, 2);
        mega<<<64, 256, 0, stream>>>(x, W, bvec, ew, erow, ecol, sshr, sshs, acc, outp,
                                     Ntot, npg, epg, 0, nmask, 3);
    }
}

// Round 10
// 176.400 us; speedup vs baseline: 2.8946x; 2.8946x over previous
//
#include <hip/hip_runtime.h>
#include <math.h>
#include <stdint.h>

#define F_DIM 64
#define K_CL 16
#define B_GR 16
#define SR32 68   // LDS row stride in u32: read 8-way-minimal, write conflict-free

typedef _Float16 h16;
using f16x8 = __attribute__((ext_vector_type(8))) _Float16;
using f16x2 = __attribute__((ext_vector_type(2))) _Float16;
using f32x4 = __attribute__((ext_vector_type(4))) float;

union HU { h16 f; unsigned short u; };
union PU { uint32_t u; f16x2 v; };
union H8 { f16x8 v; uint32_t u[4]; };

// ---------------------------------------------------------------------------
// K1: fused assign + node stats.
// Phase A (thread=node): s = xW+b (fp32), softmax, stage s/ss fp32 in LDS,
//   write ssq = e5m2(ss) global (16 B/node).
// Phase B (wave reads its own 64 staged nodes): outx += s^T x (fp32, x
//   re-read is L1-hot), CC += ss^T ss. Block reduce, global atomics.
// cluster_size = CC row sums (softmax rows sum to 1) -> not materialized.
// ---------------------------------------------------------------------------
__global__ __launch_bounds__(256) void k_fused(
    const float* __restrict__ x, const float* __restrict__ W, const float* __restrict__ bvec,
    uint32_t* __restrict__ ssq, float* __restrict__ outx, float* __restrict__ CCb)
{
    __shared__ float Wl[F_DIM * K_CL];
    __shared__ float bl[K_CL];
    __shared__ __align__(16) float Ss[256 * 20];   // sraw, stride 20 (20 KB)
    __shared__ __align__(16) float Cs[256 * 20];   // ss,   stride 20 (20 KB)
    __shared__ float CCl[256];

    int t = threadIdx.x;
    for (int idx = t; idx < F_DIM * K_CL; idx += 256) Wl[idx] = W[idx];
    if (t < K_CL) bl[t] = bvec[t];
    CCl[t] = 0.f;
    __syncthreads();

    int wid = t >> 6, lane = t & 63;
    int bid = blockIdx.x;

    // ---------------- Phase A ----------------
    {
        size_t i = (size_t)bid * 256 + t;
        float s[16];
#pragma unroll
        for (int k = 0; k < 16; ++k) s[k] = bl[k];

        const float4* xp = reinterpret_cast<const float4*>(x + i * F_DIM);
#pragma unroll
        for (int j = 0; j < 16; ++j) {
            float4 q = xp[j];
            float xf[4] = {q.x, q.y, q.z, q.w};
#pragma unroll
            for (int ff = 0; ff < 4; ++ff) {
                int f = j * 4 + ff;
                float xv = xf[ff];
                const float4* wr = reinterpret_cast<const float4*>(&Wl[f * K_CL]);
                float4 w0 = wr[0], w1 = wr[1], w2 = wr[2], w3 = wr[3];
                s[0]  += xv * w0.x; s[1]  += xv * w0.y; s[2]  += xv * w0.z; s[3]  += xv * w0.w;
                s[4]  += xv * w1.x; s[5]  += xv * w1.y; s[6]  += xv * w1.z; s[7]  += xv * w1.w;
                s[8]  += xv * w2.x; s[9]  += xv * w2.y; s[10] += xv * w2.z; s[11] += xv * w2.w;
                s[12] += xv * w3.x; s[13] += xv * w3.y; s[14] += xv * w3.z; s[15] += xv * w3.w;
            }
        }

        // stage sraw fp32
        float4* sp = reinterpret_cast<float4*>(&Ss[t * 20]);
        sp[0] = make_float4(s[0], s[1], s[2], s[3]);
        sp[1] = make_float4(s[4], s[5], s[6], s[7]);
        sp[2] = make_float4(s[8], s[9], s[10], s[11]);
        sp[3] = make_float4(s[12], s[13], s[14], s[15]);

        // softmax
        float m = s[0];
#pragma unroll
        for (int k = 1; k < 16; ++k) m = fmaxf(m, s[k]);
        float sum = 0.f;
#pragma unroll
        for (int k = 0; k < 16; ++k) { s[k] = __expf(s[k] - m); sum += s[k]; }
        float inv = 1.0f / sum;
#pragma unroll
        for (int k = 0; k < 16; ++k) s[k] *= inv;

        float4* cp = reinterpret_cast<float4*>(&Cs[t * 20]);
        cp[0] = make_float4(s[0], s[1], s[2], s[3]);
        cp[1] = make_float4(s[4], s[5], s[6], s[7]);
        cp[2] = make_float4(s[8], s[9], s[10], s[11]);
        cp[3] = make_float4(s[12], s[13], s[14], s[15]);

        // quantize ss -> e5m2 (top byte of f16, round-to-nearest), pack 4/u32
        uint32_t g[4];
#pragma unroll
        for (int i4 = 0; i4 < 4; ++i4) {
            uint32_t acc = 0;
#pragma unroll
            for (int j4 = 0; j4 < 4; ++j4) {
                HU h; h.f = (h16)s[i4 * 4 + j4];
                uint32_t u = h.u;
                uint32_t b = (u + 0x7Fu + ((u >> 7) & 1u)) >> 8;
                acc |= (b & 0xFFu) << (8 * j4);
            }
            g[i4] = acc;
        }
        *reinterpret_cast<uint4*>(ssq + i * 4) = make_uint4(g[0], g[1], g[2], g[3]);
    }

    // ---------------- Phase B (wave-private staged nodes) ----------------
    float accx[16];
#pragma unroll
    for (int k = 0; k < 16; ++k) accx[k] = 0.f;
    float accc[4] = {0.f, 0.f, 0.f, 0.f};
    int g4 = lane >> 4, l = lane & 15;
    size_t xbase = ((size_t)bid * 256 + wid * 64) * F_DIM;

    for (int j = 0; j < 64; ++j) {
        int node = wid * 64 + j;
        float xv = x[xbase + (size_t)j * F_DIM + lane];   // L1-hot re-read
        const float4* sp = reinterpret_cast<const float4*>(&Ss[node * 20]);
        float4 s0 = sp[0], s1 = sp[1], s2 = sp[2], s3 = sp[3];   // broadcast
        accx[0]  += s0.x * xv; accx[1]  += s0.y * xv; accx[2]  += s0.z * xv; accx[3]  += s0.w * xv;
        accx[4]  += s1.x * xv; accx[5]  += s1.y * xv; accx[6]  += s1.z * xv; accx[7]  += s1.w * xv;
        accx[8]  += s2.x * xv; accx[9]  += s2.y * xv; accx[10] += s2.z * xv; accx[11] += s2.w * xv;
        accx[12] += s3.x * xv; accx[13] += s3.y * xv; accx[14] += s3.z * xv; accx[15] += s3.w * xv;

        float ssl = Cs[node * 20 + l];
        float4 sq = *reinterpret_cast<const float4*>(&Cs[node * 20 + g4 * 4]);
        accc[0] += sq.x * ssl;
        accc[1] += sq.y * ssl;
        accc[2] += sq.z * ssl;
        accc[3] += sq.w * ssl;
    }

#pragma unroll
    for (int j4 = 0; j4 < 4; ++j4)
        atomicAdd(&CCl[(g4 * 4 + j4) * 16 + l], accc[j4]);
    __syncthreads();                       // all waves done reading Ss

    float* redx = Ss;                      // reuse (16 KB < 20 KB)
#pragma unroll
    for (int k = 0; k < 16; ++k) redx[wid * 1024 + k * 64 + lane] = accx[k];
    __syncthreads();

    int g = bid >> 5;                      // 32 blocks per graph
    float* dst = outx + g * (K_CL * F_DIM);
#pragma unroll
    for (int it = 0; it < 4; ++it) {
        int idx = t + it * 256;
        float v = redx[idx] + redx[1024 + idx] + redx[2048 + idx] + redx[3072 + idx];
        atomicAdd(dst + idx, v);
    }
    atomicAdd(&CCb[g * 256 + t], CCl[t]);
}

// ---------------------------------------------------------------------------
// K2: oadj via MFMA. ssq rows are 16 B e5m2 -> ONE dwordx4 gather per row
// (2 per edge, was 4). Decode = 2 int ops per 4 values; fold w via pk_mul;
// u32-packed (A|B) LDS staging at stride SR32 (write 2-way-free, read
// 8-way-minimal); 4 ds_read_b128 + 2 MFMA per 64 edges.
// ---------------------------------------------------------------------------
__global__ __launch_bounds__(256) void k_edge(
    const int* __restrict__ erow, const int* __restrict__ ecol, const float* __restrict__ ew,
    const uint32_t* __restrict__ ssq, float* __restrict__ oadj,
    int edges_per_block, int edges_per_graph, int nmask)
{
    __shared__ float CCl[256];
    __shared__ __align__(16) uint32_t AB[4][16 * SR32];   // 17.4 KB
    int t = threadIdx.x;
    CCl[t] = 0.f;
    __syncthreads();

    int bid = blockIdx.x;
    int xcd = bid & 7;
    int slot = bid >> 3;
    int graph = xcd + 8 * (slot & 1);
    int chunk = slot >> 1;

    int wid = t >> 6, lane = t & 63;
    int q4 = lane >> 4, mm = lane & 15;
    uint32_t* ABw = AB[wid];

    int epw = edges_per_block >> 2;
    size_t base = (size_t)graph * edges_per_graph
                + (size_t)chunk * edges_per_block
                + (size_t)wid * epw;

    f32x4 acc = {0.f, 0.f, 0.f, 0.f};

    for (int e0 = 0; e0 < epw; e0 += 64) {
        size_t eb = base + e0 + lane;
        int   r = erow[eb] & nmask;
        int   c = ecol[eb] & nmask;
        float w = ew[eb];

        uint4 ga = *reinterpret_cast<const uint4*>(ssq + (size_t)r * 4);
        uint4 gb = *reinterpret_cast<const uint4*>(ssq + (size_t)c * 4);

        // decode e5m2 bytes -> f16 pairs: src u32 i holds m = 4i..4i+3;
        // lo pair = (m4i, m4i+2), hi pair = (m4i+1, m4i+3)
        uint32_t pa[8], pb[8];
        uint32_t gaw[4] = {ga.x, ga.y, ga.z, ga.w};
        uint32_t gbw[4] = {gb.x, gb.y, gb.z, gb.w};
#pragma unroll
        for (int i4 = 0; i4 < 4; ++i4) {
            pa[2 * i4]     = (gaw[i4] << 8) & 0xFF00FF00u;
            pa[2 * i4 + 1] =  gaw[i4]       & 0xFF00FF00u;
            pb[2 * i4]     = (gbw[i4] << 8) & 0xFF00FF00u;
            pb[2 * i4 + 1] =  gbw[i4]       & 0xFF00FF00u;
        }

        // fold w into A (packed f16 mul)
        HU wh; wh.f = (h16)w;
        PU wp; wp.u = (uint32_t)wh.u | ((uint32_t)wh.u << 16);
#pragma unroll
        for (int i8 = 0; i8 < 8; ++i8) {
            PU a; a.u = pa[i8];
            a.v = a.v * wp.v;
            pa[i8] = a.u;
        }

        // interleave to (A_m | B_m<<16) words, write to LDS row m
#pragma unroll
        for (int i4 = 0; i4 < 4; ++i4) {
            uint32_t alo = pa[2 * i4], ahi = pa[2 * i4 + 1];
            uint32_t blo = pb[2 * i4], bhi = pb[2 * i4 + 1];
            ABw[(4 * i4 + 0) * SR32 + lane] = (alo & 0xFFFFu) | (blo << 16);
            ABw[(4 * i4 + 1) * SR32 + lane] = (ahi & 0xFFFFu) | (bhi << 16);
            ABw[(4 * i4 + 2) * SR32 + lane] = (alo >> 16) | (bhi & 0u) | (blo & 0xFFFF0000u);
            ABw[(4 * i4 + 3) * SR32 + lane] = (ahi >> 16) | (bhi & 0xFFFF0000u);
        }

#pragma unroll
        for (int h = 0; h < 2; ++h) {
            const uint32_t* rowp = &ABw[mm * SR32 + h * 32 + q4 * 8];
            uint4 p0 = *reinterpret_cast<const uint4*>(rowp);
            uint4 p1 = *reinterpret_cast<const uint4*>(rowp + 4);
            H8 Af, Bf;
            Af.u[0] = (p0.x & 0xFFFFu) | (p0.y << 16);
            Bf.u[0] = (p0.x >> 16)     | (p0.y & 0xFFFF0000u);
            Af.u[1] = (p0.z & 0xFFFFu) | (p0.w << 16);
            Bf.u[1] = (p0.z >> 16)     | (p0.w & 0xFFFF0000u);
            Af.u[2] = (p1.x & 0xFFFFu) | (p1.y << 16);
            Bf.u[2] = (p1.x >> 16)     | (p1.y & 0xFFFF0000u);
            Af.u[3] = (p1.z & 0xFFFFu) | (p1.w << 16);
            Bf.u[3] = (p1.z >> 16)     | (p1.w & 0xFFFF0000u);
            acc = __builtin_amdgcn_mfma_f32_16x16x32_f16(Af.v, Bf.v, acc, 0, 0, 0);
        }
    }

#pragma unroll
    for (int rg = 0; rg < 4; ++rg)
        atomicAdd(&CCl[(q4 * 4 + rg) * 16 + mm], acc[rg]);
    __syncthreads();
    atomicAdd(oadj + graph * 256 + t, CCl[t]);
}

// ---------------------------------------------------------------------------
// K3: grid 64. All blocks: parallel selu. Block 0: losses + out_adj_norm.
// dS = column sums of oadj, m2 = total sum, cs = CC row sums.
// ---------------------------------------------------------------------------
__global__ __launch_bounds__(256) void k_final(
    const float* __restrict__ outx, const float* __restrict__ oadj,
    const float* __restrict__ CCb, float* __restrict__ out, int npg)
{
    int t = threadIdx.x;
    int gid = blockIdx.x * 256 + t;
    {
        float v = outx[gid];
        float r = (v > 0.f) ? (1.0507009873554805f * v)
                            : (1.0507009873554805f * 1.6732632423543772f * (__expf(v) - 1.0f));
        out[gid] = r;
    }

    if (blockIdx.x != 0) return;

    int b = t >> 4, k = t & 15;
    const float* oar = oadj + b * 256 + k * 16;
    const float* ccr = CCb + b * 256 + k * 16;

    float rowsum_off = 0.f, trace_c = 0.f, rowsum_all = 0.f, fro2 = 0.f, colsum = 0.f;
    float csv = 0.f;
#pragma unroll
    for (int l = 0; l < 16; ++l) {
        float v = oar[l];
        rowsum_all += v;
        if (l == k) trace_c = v; else rowsum_off += v;
        float c = ccr[l];
        fro2 += c * c;
        csv += c;
        colsum += oadj[b * 256 + l * 16 + k];
    }
    float dd = sqrtf(rowsum_off) + 1e-12f;
    __shared__ float ddl[B_GR * K_CL];
    ddl[t] = dd;

    float ds2 = colsum * colsum, cs2 = csv * csv;
    float tr = trace_c, m2 = rowsum_all;
#pragma unroll
    for (int msk = 8; msk >= 1; msk >>= 1) {
        tr   += __shfl_xor(tr,   msk, 16);
        ds2  += __shfl_xor(ds2,  msk, 16);
        cs2  += __shfl_xor(cs2,  msk, 16);
        fro2 += __shfl_xor(fro2, msk, 16);
        m2   += __shfl_xor(m2,   msk, 16);
    }
    float invfro = 1.0f / sqrtf(fro2);
    float osum = 0.f;
#pragma unroll
    for (int l = 0; l < 16; ++l) {
        float v = ccr[l] * invfro - ((l == k) ? 0.25f : 0.f);
        osum += v * v;
    }
#pragma unroll
    for (int msk = 8; msk >= 1; msk >>= 1) osum += __shfl_xor(osum, msk, 16);

    __shared__ float sp_s[B_GR], cl_s[B_GR], or_s[B_GR];
    if (k == 0) {
        sp_s[b] = tr / m2 - ds2 / (m2 * m2);
        cl_s[b] = sqrtf(cs2) / (float)npg * 4.0f - 1.0f;
        or_s[b] = sqrtf(osum);
    }
    __syncthreads();
    if (t == 0) {
        float a = 0.f, c = 0.f, o = 0.f;
        for (int i = 0; i < B_GR; ++i) { a += sp_s[i]; c += cl_s[i]; o += or_s[i]; }
        out[20480] = -a / 16.f;
        out[20481] = c / 16.f;
        out[20482] = o / 16.f;
    }

#pragma unroll
    for (int l = 0; l < 16; ++l) {
        float v = (l == k) ? 0.f : oar[l] / (dd * ddl[b * 16 + l]);
        out[16384 + b * 256 + k * 16 + l] = v;
    }
}

// ---------------------------------------------------------------------------
extern "C" void kernel_launch(void* const* d_in, const int* in_sizes, int n_in,
                              void* d_out, int out_size, void* d_ws, size_t ws_size,
                              hipStream_t stream)
{
    const float* x    = (const float*)d_in[0];
    const float* W    = (const float*)d_in[1];
    const float* bvec = (const float*)d_in[2];
    const float* ew   = (const float*)d_in[3];
    const int* erow   = (const int*)d_in[4];
    const int* ecol   = (const int*)d_in[5];

    int Ntot = in_sizes[0] / F_DIM;           // 131072
    size_t E = (size_t)in_sizes[3];           // 4194304
    int npg  = Ntot / B_GR;                   // 8192
    int edges_per_graph = (int)(E / B_GR);    // 262144
    int nmask = Ntot - 1;

    const int ADJ_BLOCKS = 2048;              // 8 blocks/CU (18.4 KB LDS each)
    int edges_per_block = (int)(E / ADJ_BLOCKS);          // 2048

    char* ws = (char*)d_ws;
    size_t o = 0;
    uint32_t* ssq = (uint32_t*)(ws + o); o += (size_t)Ntot * 16;  // e5m2, 16 B/node
    size_t zoff = o;
    float* outx = (float*)(ws + o); o += (size_t)B_GR * 1024 * 4;
    float* oadj = (float*)(ws + o); o += (size_t)B_GR * 256 * 4;
    float* CCb  = (float*)(ws + o); o += (size_t)B_GR * 256 * 4;

    hipMemsetAsync(ws + zoff, 0, o - zoff, stream);

    k_fused<<<Ntot / 256, 256, 0, stream>>>(x, W, bvec, ssq, outx, CCb);
    k_edge<<<ADJ_BLOCKS, 256, 0, stream>>>(erow, ecol, ew, ssq, oadj,
                                           edges_per_block, edges_per_graph, nmask);
    k_final<<<64, 256, 0, stream>>>(outx, oadj, CCb, (float*)d_out, npg);
}

// Round 11
// 172.194 us; speedup vs baseline: 2.9653x; 1.0244x over previous
//
#include <hip/hip_runtime.h>
#include <math.h>
#include <stdint.h>

#define F_DIM 64
#define K_CL 16
#define B_GR 16
#define SR32 68   // LDS row stride in u32: write conflict-free, read 2-way

typedef _Float16 h16;
using f16x8 = __attribute__((ext_vector_type(8))) _Float16;
using f16x2 = __attribute__((ext_vector_type(2))) _Float16;
using f32x4 = __attribute__((ext_vector_type(4))) float;

union HU { h16 f; unsigned short u; };
union PU { uint32_t u; f16x2 v; };
union H8 { f16x8 v; uint32_t u[4]; };

// ---------------------------------------------------------------------------
// K1: fused assign + node stats.
// Phase A (thread=node): s = xW+b (fp32), softmax, stage sraw fp32 + ss f16x2
//   in LDS, write ssq = e5m2(ss) global (16 B/node).
// Phase B (wave=64 own nodes, lane=f): outx += sraw^T x (fp32, broadcast LDS
//   reads), CC += ss^T ss (f16 in, fp32 acc). Block reduce, global atomics.
// cluster_size = CC row sums (softmax rows sum to 1) -> not materialized.
// ---------------------------------------------------------------------------
__global__ __launch_bounds__(256) void k_fused(
    const float* __restrict__ x, const float* __restrict__ W, const float* __restrict__ bvec,
    uint32_t* __restrict__ ssq, float* __restrict__ outx, float* __restrict__ CCb)
{
    __shared__ float Wl[F_DIM * K_CL];
    __shared__ float bl[K_CL];
    __shared__ __align__(16) float Ss[256 * 20];      // sraw fp32 (20 KB)
    __shared__ uint32_t Csu[256 * 9];                 // ss f16x2 (9 KB)
    __shared__ float CCl[256];

    int t = threadIdx.x;
    for (int idx = t; idx < F_DIM * K_CL; idx += 256) Wl[idx] = W[idx];
    if (t < K_CL) bl[t] = bvec[t];
    CCl[t] = 0.f;
    __syncthreads();

    int wid = t >> 6, lane = t & 63;
    int bid = blockIdx.x;

    // ---------------- Phase A ----------------
    {
        size_t i = (size_t)bid * 256 + t;
        float s[16];
#pragma unroll
        for (int k = 0; k < 16; ++k) s[k] = bl[k];

        const float4* xp = reinterpret_cast<const float4*>(x + i * F_DIM);
#pragma unroll
        for (int j = 0; j < 16; ++j) {
            float4 q = xp[j];
            float xf[4] = {q.x, q.y, q.z, q.w};
#pragma unroll
            for (int ff = 0; ff < 4; ++ff) {
                int f = j * 4 + ff;
                float xv = xf[ff];
                const float4* wr = reinterpret_cast<const float4*>(&Wl[f * K_CL]);
                float4 w0 = wr[0], w1 = wr[1], w2 = wr[2], w3 = wr[3];
                s[0]  += xv * w0.x; s[1]  += xv * w0.y; s[2]  += xv * w0.z; s[3]  += xv * w0.w;
                s[4]  += xv * w1.x; s[5]  += xv * w1.y; s[6]  += xv * w1.z; s[7]  += xv * w1.w;
                s[8]  += xv * w2.x; s[9]  += xv * w2.y; s[10] += xv * w2.z; s[11] += xv * w2.w;
                s[12] += xv * w3.x; s[13] += xv * w3.y; s[14] += xv * w3.z; s[15] += xv * w3.w;
            }
        }

        float4* sp = reinterpret_cast<float4*>(&Ss[t * 20]);
        sp[0] = make_float4(s[0], s[1], s[2], s[3]);
        sp[1] = make_float4(s[4], s[5], s[6], s[7]);
        sp[2] = make_float4(s[8], s[9], s[10], s[11]);
        sp[3] = make_float4(s[12], s[13], s[14], s[15]);

        float m = s[0];
#pragma unroll
        for (int k = 1; k < 16; ++k) m = fmaxf(m, s[k]);
        float sum = 0.f;
#pragma unroll
        for (int k = 0; k < 16; ++k) { s[k] = __expf(s[k] - m); sum += s[k]; }
        float inv = 1.0f / sum;
#pragma unroll
        for (int k = 0; k < 16; ++k) s[k] *= inv;

        // stage ss as f16x2
#pragma unroll
        for (int p = 0; p < 8; ++p) {
            PU u;
            u.v[0] = (h16)s[2 * p];
            u.v[1] = (h16)s[2 * p + 1];
            Csu[t * 9 + p] = u.u;
        }

        // quantize ss -> e5m2 (top byte of f16, RTNE), 4 per u32
        uint32_t g[4];
#pragma unroll
        for (int i4 = 0; i4 < 4; ++i4) {
            uint32_t acc = 0;
#pragma unroll
            for (int j4 = 0; j4 < 4; ++j4) {
                HU h; h.f = (h16)s[i4 * 4 + j4];
                uint32_t u = h.u;
                uint32_t b = (u + 0x7Fu + ((u >> 7) & 1u)) >> 8;
                acc |= (b & 0xFFu) << (8 * j4);
            }
            g[i4] = acc;
        }
        *reinterpret_cast<uint4*>(ssq + i * 4) = make_uint4(g[0], g[1], g[2], g[3]);
    }
    __syncthreads();

    // ---------------- Phase B (wave-private staged nodes) ----------------
    float accx[16];
#pragma unroll
    for (int k = 0; k < 16; ++k) accx[k] = 0.f;
    float accc[4] = {0.f, 0.f, 0.f, 0.f};
    int g4 = lane >> 4, l = lane & 15;
    size_t xbase = ((size_t)bid * 256 + wid * 64) * F_DIM;

    for (int j = 0; j < 64; ++j) {
        int node = wid * 64 + j;
        float xv = x[xbase + (size_t)j * F_DIM + lane];   // coalesced, L1/L2-hot
        const float4* sp = reinterpret_cast<const float4*>(&Ss[node * 20]);
        float4 s0 = sp[0], s1 = sp[1], s2 = sp[2], s3 = sp[3];   // broadcast
        accx[0]  += s0.x * xv; accx[1]  += s0.y * xv; accx[2]  += s0.z * xv; accx[3]  += s0.w * xv;
        accx[4]  += s1.x * xv; accx[5]  += s1.y * xv; accx[6]  += s1.z * xv; accx[7]  += s1.w * xv;
        accx[8]  += s2.x * xv; accx[9]  += s2.y * xv; accx[10] += s2.z * xv; accx[11] += s2.w * xv;
        accx[12] += s3.x * xv; accx[13] += s3.y * xv; accx[14] += s3.z * xv; accx[15] += s3.w * xv;

        const uint32_t* cp = &Csu[node * 9];
        PU pl; pl.u = cp[l >> 1];
        float ssl = (float)pl.v[l & 1];
        PU q0; q0.u = cp[g4 * 2];
        PU q1; q1.u = cp[g4 * 2 + 1];
        accc[0] += (float)q0.v[0] * ssl;
        accc[1] += (float)q0.v[1] * ssl;
        accc[2] += (float)q1.v[0] * ssl;
        accc[3] += (float)q1.v[1] * ssl;
    }

#pragma unroll
    for (int j4 = 0; j4 < 4; ++j4)
        atomicAdd(&CCl[(g4 * 4 + j4) * 16 + l], accc[j4]);
    __syncthreads();                       // all waves done reading Ss

    float* redx = Ss;                      // reuse (16 KB < 20 KB)
#pragma unroll
    for (int k = 0; k < 16; ++k) redx[wid * 1024 + k * 64 + lane] = accx[k];
    __syncthreads();

    int g = bid >> 5;                      // 32 blocks per graph
    float* dst = outx + g * (K_CL * F_DIM);
#pragma unroll
    for (int it = 0; it < 4; ++it) {
        int idx = t + it * 256;
        float v = redx[idx] + redx[1024 + idx] + redx[2048 + idx] + redx[3072 + idx];
        atomicAdd(dst + idx, v);
    }
    atomicAdd(&CCb[g * 256 + t], CCl[t]);
}

// ---------------------------------------------------------------------------
// K2: oadj via MFMA, e5m2 16 B rows, depth-2 software pipeline:
// edges prefetched 2 iters ahead, ssq gathers 1 iter ahead — each memory
// wait overlaps a full decode+LDS+MFMA body of the previous iteration.
// ---------------------------------------------------------------------------
__global__ __launch_bounds__(256) void k_edge(
    const int* __restrict__ erow, const int* __restrict__ ecol, const float* __restrict__ ew,
    const uint32_t* __restrict__ ssq, float* __restrict__ oadj,
    int edges_per_block, int edges_per_graph, int nmask)
{
    __shared__ float CCl[256];
    __shared__ __align__(16) uint32_t AB[4][16 * SR32];   // 17.4 KB
    int t = threadIdx.x;
    CCl[t] = 0.f;
    __syncthreads();

    int bid = blockIdx.x;
    int xcd = bid & 7;
    int slot = bid >> 3;
    int graph = xcd + 8 * (slot & 1);
    int chunk = slot >> 1;

    int wid = t >> 6, lane = t & 63;
    int q4 = lane >> 4, mm = lane & 15;
    uint32_t* ABw = AB[wid];

    int epw = edges_per_block >> 2;
    int iters = epw >> 6;
    size_t base = (size_t)graph * edges_per_graph
                + (size_t)chunk * edges_per_block
                + (size_t)wid * epw;

    const uint4* ssqv = reinterpret_cast<const uint4*>(ssq);
    f32x4 acc = {0.f, 0.f, 0.f, 0.f};

    // pipeline state: current (gathers in flight/loaded), next (edges loaded)
    int r_c, c_c, r_n = 0, c_n = 0;
    float w_c, w_n = 0.f;
    uint4 ga_c, gb_c;

    {
        size_t e0 = base + lane;
        r_c = erow[e0] & nmask; c_c = ecol[e0] & nmask; w_c = ew[e0];
        ga_c = ssqv[r_c]; gb_c = ssqv[c_c];
        if (iters > 1) {
            size_t e1 = e0 + 64;
            r_n = erow[e1] & nmask; c_n = ecol[e1] & nmask; w_n = ew[e1];
        }
    }

    for (int i = 0; i < iters; ++i) {
        // issue gathers for i+1 (edges i+1 have been in flight one body)
        uint4 ga_n, gb_n;
        if (i + 1 < iters) { ga_n = ssqv[r_n]; gb_n = ssqv[c_n]; }
        // issue edge loads for i+2
        int r_nn = 0, c_nn = 0;
        float w_nn = 0.f;
        if (i + 2 < iters) {
            size_t e2 = base + (size_t)(i + 2) * 64 + lane;
            r_nn = erow[e2] & nmask; c_nn = ecol[e2] & nmask; w_nn = ew[e2];
        }

        // consume current: decode e5m2 -> f16, fold w, LDS transpose, MFMA
        uint32_t pa[8], pb[8];
        uint32_t gaw[4] = {ga_c.x, ga_c.y, ga_c.z, ga_c.w};
        uint32_t gbw[4] = {gb_c.x, gb_c.y, gb_c.z, gb_c.w};
#pragma unroll
        for (int i4 = 0; i4 < 4; ++i4) {
            pa[2 * i4]     = (gaw[i4] << 8) & 0xFF00FF00u;
            pa[2 * i4 + 1] =  gaw[i4]       & 0xFF00FF00u;
            pb[2 * i4]     = (gbw[i4] << 8) & 0xFF00FF00u;
            pb[2 * i4 + 1] =  gbw[i4]       & 0xFF00FF00u;
        }

        HU wh; wh.f = (h16)w_c;
        PU wp; wp.u = (uint32_t)wh.u | ((uint32_t)wh.u << 16);
#pragma unroll
        for (int i8 = 0; i8 < 8; ++i8) {
            PU a; a.u = pa[i8];
            a.v = a.v * wp.v;
            pa[i8] = a.u;
        }

#pragma unroll
        for (int i4 = 0; i4 < 4; ++i4) {
            uint32_t alo = pa[2 * i4], ahi = pa[2 * i4 + 1];
            uint32_t blo = pb[2 * i4], bhi = pb[2 * i4 + 1];
            ABw[(4 * i4 + 0) * SR32 + lane] = (alo & 0xFFFFu) | (blo << 16);
            ABw[(4 * i4 + 1) * SR32 + lane] = (ahi & 0xFFFFu) | (bhi << 16);
            ABw[(4 * i4 + 2) * SR32 + lane] = (alo >> 16) | (blo & 0xFFFF0000u);
            ABw[(4 * i4 + 3) * SR32 + lane] = (ahi >> 16) | (bhi & 0xFFFF0000u);
        }

#pragma unroll
        for (int h = 0; h < 2; ++h) {
            const uint32_t* rowp = &ABw[mm * SR32 + h * 32 + q4 * 8];
            uint4 p0 = *reinterpret_cast<const uint4*>(rowp);
            uint4 p1 = *reinterpret_cast<const uint4*>(rowp + 4);
            H8 Af, Bf;
            Af.u[0] = (p0.x & 0xFFFFu) | (p0.y << 16);
            Bf.u[0] = (p0.x >> 16)     | (p0.y & 0xFFFF0000u);
            Af.u[1] = (p0.z & 0xFFFFu) | (p0.w << 16);
            Bf.u[1] = (p0.z >> 16)     | (p0.w & 0xFFFF0000u);
            Af.u[2] = (p1.x & 0xFFFFu) | (p1.y << 16);
            Bf.u[2] = (p1.x >> 16)     | (p1.y & 0xFFFF0000u);
            Af.u[3] = (p1.z & 0xFFFFu) | (p1.w << 16);
            Bf.u[3] = (p1.z >> 16)     | (p1.w & 0xFFFF0000u);
            acc = __builtin_amdgcn_mfma_f32_16x16x32_f16(Af.v, Bf.v, acc, 0, 0, 0);
        }

        // rotate pipeline
        r_c = r_n; c_c = c_n; w_c = w_n;
        ga_c = ga_n; gb_c = gb_n;
        r_n = r_nn; c_n = c_nn; w_n = w_nn;
    }

#pragma unroll
    for (int rg = 0; rg < 4; ++rg)
        atomicAdd(&CCl[(q4 * 4 + rg) * 16 + mm], acc[rg]);
    __syncthreads();
    atomicAdd(oadj + graph * 256 + t, CCl[t]);
}

// ---------------------------------------------------------------------------
// K3: grid 64. All blocks: parallel selu. Block 0: losses + out_adj_norm.
// dS = column sums of oadj, m2 = total sum, cs = CC row sums.
// ---------------------------------------------------------------------------
__global__ __launch_bounds__(256) void k_final(
    const float* __restrict__ outx, const float* __restrict__ oadj,
    const float* __restrict__ CCb, float* __restrict__ out, int npg)
{
    int t = threadIdx.x;
    int gid = blockIdx.x * 256 + t;
    {
        float v = outx[gid];
        float r = (v > 0.f) ? (1.0507009873554805f * v)
                            : (1.0507009873554805f * 1.6732632423543772f * (__expf(v) - 1.0f));
        out[gid] = r;
    }

    if (blockIdx.x != 0) return;

    int b = t >> 4, k = t & 15;
    const float* oar = oadj + b * 256 + k * 16;
    const float* ccr = CCb + b * 256 + k * 16;

    float rowsum_off = 0.f, trace_c = 0.f, rowsum_all = 0.f, fro2 = 0.f, colsum = 0.f;
    float csv = 0.f;
#pragma unroll
    for (int l = 0; l < 16; ++l) {
        float v = oar[l];
        rowsum_all += v;
        if (l == k) trace_c = v; else rowsum_off += v;
        float c = ccr[l];
        fro2 += c * c;
        csv += c;
        colsum += oadj[b * 256 + l * 16 + k];
    }
    float dd = sqrtf(rowsum_off) + 1e-12f;
    __shared__ float ddl[B_GR * K_CL];
    ddl[t] = dd;

    float ds2 = colsum * colsum, cs2 = csv * csv;
    float tr = trace_c, m2 = rowsum_all;
#pragma unroll
    for (int msk = 8; msk >= 1; msk >>= 1) {
        tr   += __shfl_xor(tr,   msk, 16);
        ds2  += __shfl_xor(ds2,  msk, 16);
        cs2  += __shfl_xor(cs2,  msk, 16);
        fro2 += __shfl_xor(fro2, msk, 16);
        m2   += __shfl_xor(m2,   msk, 16);
    }
    float invfro = 1.0f / sqrtf(fro2);
    float osum = 0.f;
#pragma unroll
    for (int l = 0; l < 16; ++l) {
        float v = ccr[l] * invfro - ((l == k) ? 0.25f : 0.f);
        osum += v * v;
    }
#pragma unroll
    for (int msk = 8; msk >= 1; msk >>= 1) osum += __shfl_xor(osum, msk, 16);

    __shared__ float sp_s[B_GR], cl_s[B_GR], or_s[B_GR];
    if (k == 0) {
        sp_s[b] = tr / m2 - ds2 / (m2 * m2);
        cl_s[b] = sqrtf(cs2) / (float)npg * 4.0f - 1.0f;
        or_s[b] = sqrtf(osum);
    }
    __syncthreads();
    if (t == 0) {
        float a = 0.f, c = 0.f, o = 0.f;
        for (int i = 0; i < B_GR; ++i) { a += sp_s[i]; c += cl_s[i]; o += or_s[i]; }
        out[20480] = -a / 16.f;
        out[20481] = c / 16.f;
        out[20482] = o / 16.f;
    }

#pragma unroll
    for (int l = 0; l < 16; ++l) {
        float v = (l == k) ? 0.f : oar[l] / (dd * ddl[b * 16 + l]);
        out[16384 + b * 256 + k * 16 + l] = v;
    }
}

// ---------------------------------------------------------------------------
extern "C" void kernel_launch(void* const* d_in, const int* in_sizes, int n_in,
                              void* d_out, int out_size, void* d_ws, size_t ws_size,
                              hipStream_t stream)
{
    const float* x    = (const float*)d_in[0];
    const float* W    = (const float*)d_in[1];
    const float* bvec = (const float*)d_in[2];
    const float* ew   = (const float*)d_in[3];
    const int* erow   = (const int*)d_in[4];
    const int* ecol   = (const int*)d_in[5];

    int Ntot = in_sizes[0] / F_DIM;           // 131072
    size_t E = (size_t)in_sizes[3];           // 4194304
    int npg  = Ntot / B_GR;                   // 8192
    int edges_per_graph = (int)(E / B_GR);    // 262144
    int nmask = Ntot - 1;

    const int ADJ_BLOCKS = 2048;              // 8 blocks/CU (17.4 KB LDS each)
    int edges_per_block = (int)(E / ADJ_BLOCKS);          // 2048

    char* ws = (char*)d_ws;
    size_t o = 0;
    uint32_t* ssq = (uint32_t*)(ws + o); o += (size_t)Ntot * 16;  // e5m2, 16 B/node
    size_t zoff = o;
    float* outx = (float*)(ws + o); o += (size_t)B_GR * 1024 * 4;
    float* oadj = (float*)(ws + o); o += (size_t)B_GR * 256 * 4;
    float* CCb  = (float*)(ws + o); o += (size_t)B_GR * 256 * 4;

    hipMemsetAsync(ws + zoff, 0, o - zoff, stream);

    k_fused<<<Ntot / 256, 256, 0, stream>>>(x, W, bvec, ssq, outx, CCb);
    k_edge<<<ADJ_BLOCKS, 256, 0, stream>>>(erow, ecol, ew, ssq, oadj,
                                           edges_per_block, edges_per_graph, nmask);
    k_final<<<64, 256, 0, stream>>>(outx, oadj, CCb, (float*)d_out, npg);
}